// Round 1
// baseline (610.307 us; speedup 1.0000x reference)
//
#include <hip/hip_runtime.h>
#include <math.h>

#define B_   16
#define L_   128
#define O_   128
#define N_   256
#define S_   64
#define U_   32
#define DEL_ 64
#define HID_ 512
#define CH_  288          // N_+U_
#define M_   2048         // B_*L_
#define KD_  288          // GEMM K for the Wg projections
#define CM_BASE (DEL_ + N_*U_)   // 8256

__device__ __forceinline__ float silu_f(float x){ return x / (1.f + expf(-x)); }
__device__ __forceinline__ float softplus_f(float x){
  // jax.nn.softplus = logaddexp(x,0), stable form
  return fmaxf(x, 0.f) + log1pf(expf(-fabsf(x)));
}

// ---------------- pack x rows (b,t<128) -> Xp (2048 x 64) ----------------
__global__ void k_pack(const float* __restrict__ x, float* __restrict__ Xp){
  int i = blockIdx.x*256 + threadIdx.x;
  if (i >= M_*S_) return;
  int m = i >> 6, c = i & 63;
  int b = m >> 7, t = m & 127;
  Xp[i] = x[((b<<8) + t)*S_ + c];   // x row stride 256
}

// ---------------- generic TN GEMM: C[m,n] = sum_k A[m,k]*B[n,k] + bias[n] ----------------
// 256 threads, 64x64 tile, kc=32, 4x4 per thread. Requires M%64==0, N%64==0, K%32==0, K%4==0.
#define GEMM_LOAD_TILES(AB, BB, KLD)                                               \
  { _Pragma("unroll")                                                              \
    for (int q = 0; q < 2; q++) {                                                  \
      int idx = tid + q*256; int row = idx >> 3; int c4 = idx & 7;                 \
      float4 av = *(const float4*)((AB) + (size_t)row*(KLD) + kk + c4*4);          \
      float4 bv = *(const float4*)((BB) + (size_t)row*(KLD) + kk + c4*4);          \
      As[c4*4+0][row]=av.x; As[c4*4+1][row]=av.y;                                  \
      As[c4*4+2][row]=av.z; As[c4*4+3][row]=av.w;                                  \
      Bs[c4*4+0][row]=bv.x; Bs[c4*4+1][row]=bv.y;                                  \
      Bs[c4*4+2][row]=bv.z; Bs[c4*4+3][row]=bv.w;                                  \
    } }

#define GEMM_MMA32()                                                               \
  { _Pragma("unroll")                                                              \
    for (int k = 0; k < 32; k++) {                                                 \
      float4 a4 = *(const float4*)&As[k][ty*4];                                    \
      float4 b4 = *(const float4*)&Bs[k][tx*4];                                    \
      float av[4] = {a4.x,a4.y,a4.z,a4.w};                                         \
      float bv[4] = {b4.x,b4.y,b4.z,b4.w};                                         \
      _Pragma("unroll") for (int i=0;i<4;i++)                                      \
        _Pragma("unroll") for (int j=0;j<4;j++)                                    \
          acc[i][j] += av[i]*bv[j];                                                \
    } }

template<int RELU>
__global__ __launch_bounds__(256) void k_gemm_tn(
    const float* __restrict__ A, const float* __restrict__ B,
    const float* __restrict__ bias, float* __restrict__ C,
    int M, int N, int K){
  __shared__ __align__(16) float As[32][68];
  __shared__ __align__(16) float Bs[32][68];
  int tid = threadIdx.x, tx = tid & 15, ty = tid >> 4;
  int nt = blockIdx.x, mt = blockIdx.y;
  const float* Ab = A + (size_t)mt*64*K;
  const float* Bb = B + (size_t)nt*64*K;
  float acc[4][4] = {};
  for (int kk = 0; kk < K; kk += 32) {
    GEMM_LOAD_TILES(Ab, Bb, K);
    __syncthreads();
    GEMM_MMA32();
    __syncthreads();
  }
  #pragma unroll
  for (int i = 0; i < 4; i++) {
    int m = mt*64 + ty*4 + i;
    float4 v; float* vv = (float*)&v;
    #pragma unroll
    for (int j = 0; j < 4; j++) {
      int n = nt*64 + tx*4 + j;
      float t = acc[i][j] + bias[n];
      vv[j] = RELU ? fmaxf(t, 0.f) : t;
    }
    *(float4*)(&C[(size_t)m*N + nt*64 + tx*4]) = v;
  }
}

// ---------------- conv (depthwise K=4) + silu -> old (2048 x 288) ----------------
__global__ void k_conv(const float* __restrict__ P, const float* __restrict__ u,
                       const float* __restrict__ cw, const float* __restrict__ cb,
                       float* __restrict__ oldb){
  int bl = blockIdx.x;          // 0..2047 = b*128+l
  int b = bl >> 7, l = bl & 127;
  int c = threadIdx.x;
  if (c >= CH_) return;
  float acc = cb[c];
  #pragma unroll
  for (int k = 0; k < 4; k++) {
    int t = l + k - 1;          // valid t in [0,126]
    if (t >= 0 && t <= O_-2) {
      float s;
      if (c < N_) s = P[((b<<7) + t)*N_ + c];
      else        s = u[((b<<8) + t)*U_ + (c - N_)];
      acc += silu_f(s) * cw[c*4 + k];
    }
  }
  oldb[(size_t)bl*CH_ + c] = silu_f(acc);
}

// ---------------- delta path: dd = softplus(draw@Wdt.T + bdt); dA, coef ----------------
__global__ __launch_bounds__(256) void k_delta(
    const float* __restrict__ draw, const float* __restrict__ Wdt,
    const float* __restrict__ bdt, const float* __restrict__ Ap,
    float* __restrict__ dA, float* __restrict__ coef){
  __shared__ float dr[16][64];
  int tid = threadIdx.x;
  int m0 = blockIdx.x * 16;
  for (int f = tid; f < 16*64; f += 256)
    dr[f>>6][f&63] = draw[(size_t)(m0 + (f>>6))*64 + (f&63)];
  __syncthreads();
  int n = tid;                        // 256 threads = 256 n
  float wrow[64];
  #pragma unroll
  for (int d = 0; d < 64; d++) wrow[d] = Wdt[n*64 + d];
  float a0 = Ap[n];
  float a = -(a0 > 0.f ? a0 : expm1f(a0));
  float inva = 1.f / a;
  float bd = bdt[n];
  for (int r = 0; r < 16; r++) {
    float s = bd;
    #pragma unroll
    for (int d = 0; d < 64; d++) s += dr[r][d] * wrow[d];
    float dd = softplus_f(s);
    float e  = expf(dd * a);
    size_t m = m0 + r;
    dA[m*N_ + n]   = e;
    coef[m*N_ + n] = (e - 1.f) * inva;   // mirrors ref's (dA-1)*(1/a)
  }
}

// ---------------- B-GEMM with fused <Bm,u0> contraction -> w (2048 x 256) ----------------
__global__ __launch_bounds__(256) void k_bgemm(
    const float* __restrict__ Aold, const float* __restrict__ Wg,
    const float* __restrict__ bg, const float* __restrict__ u,
    const float* __restrict__ coef, float* __restrict__ wout){
  __shared__ __align__(16) float As[32][68];
  __shared__ __align__(16) float Bs[32][68];
  int tid = threadIdx.x, tx = tid & 15, ty = tid >> 4;
  int rt = blockIdx.x, mt = blockIdx.y;   // rt 0..127 (64 Wg rows each = 2 n)
  const float* Ab = Aold + (size_t)mt*64*KD_;
  const float* Bb = Wg + (size_t)(DEL_ + rt*64)*KD_;
  float acc[4][4] = {};
  for (int kk = 0; kk < KD_; kk += 32) {
    GEMM_LOAD_TILES(Ab, Bb, KD_);
    __syncthreads();
    GEMM_MMA32();
    __syncthreads();
  }
  // epilogue: Bm value = acc + bg; contract with u0 over u (32 consecutive r)
  float part[4];
  #pragma unroll
  for (int i = 0; i < 4; i++) {
    int m = mt*64 + ty*4 + i;
    int b = m >> 7, l = m & 127;
    const float* urow = u + ((size_t)(b<<8) + 127 + l)*U_;  // u0[b,l,:]
    float p = 0.f;
    #pragma unroll
    for (int j = 0; j < 4; j++) {
      int rl = tx*4 + j;
      float bm = acc[i][j] + bg[DEL_ + rt*64 + rl];
      p += bm * urow[rl & 31];
    }
    part[i] = p;
  }
  #pragma unroll
  for (int d = 1; d < 8; d <<= 1) {
    #pragma unroll
    for (int i = 0; i < 4; i++) part[i] += __shfl_xor(part[i], d);
  }
  if ((tx & 7) == 0) {
    int n = rt*2 + (tx >> 3);
    #pragma unroll
    for (int i = 0; i < 4; i++) {
      size_t m = mt*64 + ty*4 + i;
      wout[m*N_ + n] = coef[m*N_ + n] * part[i];
    }
  }
}

// ---------------- sequential scan: z[b,l,n] ----------------
__global__ void k_scan(const float* __restrict__ P, const float* __restrict__ dA,
                       const float* __restrict__ w, float* __restrict__ zall){
  int b = blockIdx.x;       // 16
  int n = threadIdx.x;      // 256
  float z = P[(size_t)((b<<7) + 127)*N_ + n];   // z0 = proj(x[:,127]) (raw)
  #pragma unroll 4
  for (int l = 0; l < L_; l++) {
    size_t idx = (size_t)((b<<7) + l)*N_ + n;
    z = z * dA[idx] + w[idx];
    zall[idx] = z;
  }
}

// ---------------- C-GEMM with fused z-contraction -> partial y (atomic) ----------------
__global__ __launch_bounds__(256) void k_cgemm(
    const float* __restrict__ Aold, const float* __restrict__ Wg,
    const float* __restrict__ bg, const float* __restrict__ zall,
    float* __restrict__ y){
  __shared__ __align__(16) float As[32][68];
  __shared__ __align__(16) float Bs[32][68];
  int tid = threadIdx.x, tx = tid & 15, ty = tid >> 4;
  int g = blockIdx.x, mt = blockIdx.y;    // g: 16 groups of 16 n
  const float* Ab = Aold + (size_t)mt*64*KD_;
  float yacc[4][4] = {};
  for (int nn = 0; nn < 16; nn++) {
    int n = g*16 + nn;
    const float* Bb = Wg + (size_t)(CM_BASE + n*64)*KD_;
    float acc[4][4] = {};
    for (int kk = 0; kk < KD_; kk += 32) {
      GEMM_LOAD_TILES(Ab, Bb, KD_);
      __syncthreads();
      GEMM_MMA32();
      __syncthreads();
    }
    #pragma unroll
    for (int i = 0; i < 4; i++) {
      size_t m = mt*64 + ty*4 + i;
      float zv = zall[m*N_ + n];
      #pragma unroll
      for (int j = 0; j < 4; j++) {
        int s = tx*4 + j;
        yacc[i][j] += (acc[i][j] + bg[CM_BASE + n*64 + s]) * zv;
      }
    }
  }
  #pragma unroll
  for (int i = 0; i < 4; i++) {
    size_t m = mt*64 + ty*4 + i;
    #pragma unroll
    for (int j = 0; j < 4; j++)
      atomicAdd(&y[m*S_ + tx*4 + j], yacc[i][j]);
  }
}

// ---------------- finalize: write ys (L,B,S) into out, per-block loss partials ----------------
__global__ void k_finalize(const float* __restrict__ y, const float* __restrict__ x,
                           float* __restrict__ out, float* __restrict__ partial){
  __shared__ float red[256];
  int tid = threadIdx.x;
  float ls = 0.f;
  #pragma unroll
  for (int q = 0; q < 2; q++) {
    int e = blockIdx.x*512 + q*256 + tid;   // 0..131071, e = m*64+s
    int m = e >> 6, s = e & 63;
    int b = m >> 7, l = m & 127;
    float yv = y[e];
    out[1 + (size_t)((l<<4) + b)*S_ + s] = yv;     // ys[l,b,s]
    float xv = x[((size_t)(b<<8) + 128 + l)*S_ + s];
    float d = yv - xv;
    ls += d*d;
  }
  red[tid] = ls; __syncthreads();
  for (int st = 128; st > 0; st >>= 1) {
    if (tid < st) red[tid] += red[tid+st];
    __syncthreads();
  }
  if (tid == 0) partial[blockIdx.x] = red[0];
}

__global__ void k_loss(const float* __restrict__ partial, float* __restrict__ out){
  __shared__ float red[256];
  int tid = threadIdx.x;
  red[tid] = partial[tid]; __syncthreads();
  for (int st = 128; st > 0; st >>= 1) {
    if (tid < st) red[tid] += red[tid+st];
    __syncthreads();
  }
  if (tid == 0) out[0] = red[0] * (1.f / (float)(B_*S_*L_));
}

extern "C" void kernel_launch(void* const* d_in, const int* in_sizes, int n_in,
                              void* d_out, int out_size, void* d_ws, size_t ws_size,
                              hipStream_t stream) {
  const float* x   = (const float*)d_in[0];
  const float* u   = (const float*)d_in[1];
  const float* Ap  = (const float*)d_in[2];
  const float* W0  = (const float*)d_in[3];
  const float* b0  = (const float*)d_in[4];
  const float* W1  = (const float*)d_in[5];
  const float* b1  = (const float*)d_in[6];
  const float* cw  = (const float*)d_in[7];
  const float* cb  = (const float*)d_in[8];
  const float* Wg  = (const float*)d_in[9];
  const float* bg  = (const float*)d_in[10];
  const float* Wdt = (const float*)d_in[11];
  const float* bdt = (const float*)d_in[12];
  float* out = (float*)d_out;

  float* ws   = (float*)d_ws;
  float* Xp   = ws;                  // 2048*64   = 131072
  float* Hh   = Xp   + 131072;       // 2048*512  = 1048576
  float* Pp   = Hh   + 1048576;      // 2048*256  = 524288
  float* oldb = Pp   + 524288;       // 2048*288  = 589824
  float* draw = oldb + 589824;       // 2048*64   = 131072
  float* dA   = draw + 131072;       // 2048*256  = 524288
  float* coef = dA   + 524288;       // 2048*256  = 524288
  float* wbuf = coef + 524288;       // 2048*256  = 524288
  float* zall = wbuf + 524288;       // 2048*256  = 524288
  float* ybuf = zall + 524288;       // 2048*64   = 131072
  float* part = ybuf + 131072;       // 256

  hipMemsetAsync(ybuf, 0, (size_t)131072*sizeof(float), stream);

  // 1. pack x rows
  k_pack<<<(M_*S_ + 255)/256, 256, 0, stream>>>(x, Xp);
  // 2. H = relu(Xp @ W0.T + b0)   (2048 x 512, K=64)
  k_gemm_tn<1><<<dim3(HID_/64, M_/64), 256, 0, stream>>>(Xp, W0, b0, Hh, M_, HID_, S_);
  // 3. P = H @ W1.T + b1          (2048 x 256, K=512)
  k_gemm_tn<0><<<dim3(N_/64, M_/64), 256, 0, stream>>>(Hh, W1, b1, Pp, M_, N_, HID_);
  // 4. conv + silu -> old (2048 x 288)
  k_conv<<<M_, 320, 0, stream>>>(Pp, u, cw, cb, oldb);
  // 5. delta_raw = old @ Wg[0:64].T + bg[0:64]   (2048 x 64, K=288)
  k_gemm_tn<0><<<dim3(1, M_/64), 256, 0, stream>>>(oldb, Wg, bg, draw, M_, DEL_, KD_);
  // 6. dA, coef
  k_delta<<<M_/16, 256, 0, stream>>>(draw, Wdt, bdt, Ap, dA, coef);
  // 7. w = coef * <Bm, u0>
  k_bgemm<<<dim3(128, M_/64), 256, 0, stream>>>(oldb, Wg, bg, u, coef, wbuf);
  // 8. scan -> z
  k_scan<<<B_, N_, 0, stream>>>(Pp, dA, wbuf, zall);
  // 9. y = <Cm, z> (atomic partials over n-groups)
  k_cgemm<<<dim3(16, M_/64), 256, 0, stream>>>(oldb, Wg, bg, zall, ybuf);
  // 10. ys reorder + loss partials, 11. loss
  k_finalize<<<256, 256, 0, stream>>>(ybuf, x, out, part);
  k_loss<<<1, 256, 0, stream>>>(part, out);
}

// Round 2
// 295.184 us; speedup vs baseline: 2.0675x; 2.0675x over previous
//
#include <hip/hip_runtime.h>
#include <math.h>

#define B_   16
#define L_   128
#define O_   128
#define N_   256
#define S_   64
#define U_   32
#define DEL_ 64
#define HID_ 512
#define CH_  288          // N_+U_
#define M_   2048         // B_*L_
#define KD_  288          // GEMM K for the Wg projections
#define CM_BASE (DEL_ + N_*U_)   // 8256

typedef __bf16 bf16_t;
typedef bf16_t bf16x8 __attribute__((ext_vector_type(8)));
typedef bf16_t bf16x4 __attribute__((ext_vector_type(4)));
typedef float  f32x4  __attribute__((ext_vector_type(4)));

// address-space cast helpers for global_load_lds (CK-style uintptr reinterpret;
// LDS apertures are 2^48-aligned so low-32 truncation of a generic LDS pointer
// yields the LDS offset)
#define AS1(p) ((const __attribute__((address_space(1))) void*)(unsigned long long)(const void*)(p))
#define AS3(p) ((__attribute__((address_space(3))) void*)(unsigned int)(unsigned long long)(const void*)(p))

__device__ __forceinline__ float silu_f(float x){ return x / (1.f + expf(-x)); }
__device__ __forceinline__ float softplus_f(float x){
  return fmaxf(x, 0.f) + log1pf(expf(-fabsf(x)));
}

// ---------------- pack x rows (b,t<128) -> Xp (2048 x 64) ----------------
__global__ void k_pack(const float* __restrict__ x, float* __restrict__ Xp){
  int i = blockIdx.x*256 + threadIdx.x;
  if (i >= M_*S_) return;
  int m = i >> 6, c = i & 63;
  int b = m >> 7, t = m & 127;
  Xp[i] = x[((b<<8) + t)*S_ + c];
}

// ---------------- fp32->bf16 convert (4 elems/thread) ----------------
__global__ void k_cvt(const float* __restrict__ src, bf16_t* __restrict__ dst, int n4){
  int i = blockIdx.x*256 + threadIdx.x;
  if (i >= n4) return;
  float4 v = ((const float4*)src)[i];
  bf16x4 o;
  o[0] = (bf16_t)v.x; o[1] = (bf16_t)v.y; o[2] = (bf16_t)v.z; o[3] = (bf16_t)v.w;
  ((bf16x4*)dst)[i] = o;
}

// ---------------- fp32 TN GEMM (kept for small MLP / delta GEMMs) ----------------
#define GEMM_LOAD_TILES(AB, BB, KLD)                                               \
  { _Pragma("unroll")                                                              \
    for (int q = 0; q < 2; q++) {                                                  \
      int idx = tid + q*256; int row = idx >> 3; int c4 = idx & 7;                 \
      float4 av = *(const float4*)((AB) + (size_t)row*(KLD) + kk + c4*4);          \
      float4 bv = *(const float4*)((BB) + (size_t)row*(KLD) + kk + c4*4);          \
      As[c4*4+0][row]=av.x; As[c4*4+1][row]=av.y;                                  \
      As[c4*4+2][row]=av.z; As[c4*4+3][row]=av.w;                                  \
      Bs[c4*4+0][row]=bv.x; Bs[c4*4+1][row]=bv.y;                                  \
      Bs[c4*4+2][row]=bv.z; Bs[c4*4+3][row]=bv.w;                                  \
    } }

#define GEMM_MMA32()                                                               \
  { _Pragma("unroll")                                                              \
    for (int k = 0; k < 32; k++) {                                                 \
      float4 a4 = *(const float4*)&As[k][ty*4];                                    \
      float4 b4 = *(const float4*)&Bs[k][tx*4];                                    \
      float av[4] = {a4.x,a4.y,a4.z,a4.w};                                         \
      float bv[4] = {b4.x,b4.y,b4.z,b4.w};                                         \
      _Pragma("unroll") for (int i=0;i<4;i++)                                      \
        _Pragma("unroll") for (int j=0;j<4;j++)                                    \
          acc[i][j] += av[i]*bv[j];                                                \
    } }

template<int RELU>
__global__ __launch_bounds__(256) void k_gemm_tn(
    const float* __restrict__ A, const float* __restrict__ B,
    const float* __restrict__ bias, float* __restrict__ C,
    int M, int N, int K){
  __shared__ __align__(16) float As[32][68];
  __shared__ __align__(16) float Bs[32][68];
  int tid = threadIdx.x, tx = tid & 15, ty = tid >> 4;
  int nt = blockIdx.x, mt = blockIdx.y;
  const float* Ab = A + (size_t)mt*64*K;
  const float* Bb = B + (size_t)nt*64*K;
  float acc[4][4] = {};
  for (int kk = 0; kk < K; kk += 32) {
    GEMM_LOAD_TILES(Ab, Bb, K);
    __syncthreads();
    GEMM_MMA32();
    __syncthreads();
  }
  #pragma unroll
  for (int i = 0; i < 4; i++) {
    int m = mt*64 + ty*4 + i;
    float4 v; float* vv = (float*)&v;
    #pragma unroll
    for (int j = 0; j < 4; j++) {
      int n = nt*64 + tx*4 + j;
      float t = acc[i][j] + bias[n];
      vv[j] = RELU ? fmaxf(t, 0.f) : t;
    }
    *(float4*)(&C[(size_t)m*N + nt*64 + tx*4]) = v;
  }
}

// ---------------- conv (depthwise K=4) + silu -> old fp32 + bf16 ----------------
__global__ void k_conv(const float* __restrict__ P, const float* __restrict__ u,
                       const float* __restrict__ cw, const float* __restrict__ cb,
                       float* __restrict__ oldb, bf16_t* __restrict__ oldbf){
  int bl = blockIdx.x;          // 0..2047 = b*128+l
  int b = bl >> 7, l = bl & 127;
  int c = threadIdx.x;
  if (c >= CH_) return;
  float acc = cb[c];
  #pragma unroll
  for (int k = 0; k < 4; k++) {
    int t = l + k - 1;
    if (t >= 0 && t <= O_-2) {
      float s;
      if (c < N_) s = P[((b<<7) + t)*N_ + c];
      else        s = u[((b<<8) + t)*U_ + (c - N_)];
      acc += silu_f(s) * cw[c*4 + k];
    }
  }
  float v = silu_f(acc);
  oldb[(size_t)bl*CH_ + c]  = v;
  oldbf[(size_t)bl*CH_ + c] = (bf16_t)v;
}

// ---------------- delta path ----------------
__global__ __launch_bounds__(256) void k_delta(
    const float* __restrict__ draw, const float* __restrict__ Wdt,
    const float* __restrict__ bdt, const float* __restrict__ Ap,
    float* __restrict__ dA, float* __restrict__ coef){
  __shared__ float dr[16][64];
  int tid = threadIdx.x;
  int m0 = blockIdx.x * 16;
  for (int f = tid; f < 16*64; f += 256)
    dr[f>>6][f&63] = draw[(size_t)(m0 + (f>>6))*64 + (f&63)];
  __syncthreads();
  int n = tid;
  float wrow[64];
  #pragma unroll
  for (int d = 0; d < 64; d++) wrow[d] = Wdt[n*64 + d];
  float a0 = Ap[n];
  float a = -(a0 > 0.f ? a0 : expm1f(a0));
  float inva = 1.f / a;
  float bd = bdt[n];
  for (int r = 0; r < 16; r++) {
    float s = bd;
    #pragma unroll
    for (int d = 0; d < 64; d++) s += dr[r][d] * wrow[d];
    float dd = softplus_f(s);
    float e  = expf(dd * a);
    size_t m = m0 + r;
    dA[m*N_ + n]   = e;
    coef[m*N_ + n] = (e - 1.f) * inva;
  }
}

// ================= MFMA staging macro: 128x32 bf16 tile via global_load_lds =================
// lane i of each wave loads 16B; LDS dest = wave-uniform base + lane*16
#define STAGE_BF16(GBASE, ROW0G, LDSARR)                                            \
  { _Pragma("unroll")                                                               \
    for (int q = 0; q < 2; q++) {                                                   \
      int r0 = (wave*2 + q)*16;                                                     \
      const bf16_t* gp = (GBASE) + (size_t)((ROW0G) + r0 + srow)*KD_ + kk + scol;   \
      __builtin_amdgcn_global_load_lds(AS1(gp), AS3(&(LDSARR)[r0*32]), 16, 0, 0);   \
    } }

// ---------------- B-path MFMA: w[m,n] = coef * sum_u (old@WgB^T + bg)[m,n*32+u] * u0[m,u] ----------------
__global__ __launch_bounds__(256, 2) void k_bmfma(
    const bf16_t* __restrict__ oldbf, const bf16_t* __restrict__ Wgbf,
    const float* __restrict__ bg, const float* __restrict__ u,
    const float* __restrict__ coef, float* __restrict__ wbuf){
  __shared__ __align__(16) bf16_t Asb[128*32];
  __shared__ __align__(16) bf16_t Bsb[128*32];
  int tid = threadIdx.x;
  int wave = tid >> 6, lane = tid & 63;
  int wm = wave & 1, wn = wave >> 1;
  int mt = blockIdx.y, nt = blockIdx.x;
  int m0 = mt*128, ncol0 = nt*128;
  int srow = lane >> 2, scol = (lane & 3)*8;
  int lm = lane & 15, lq = lane >> 4;

  f32x4 acc[4][4];
  #pragma unroll
  for (int i=0;i<4;i++)
    #pragma unroll
    for (int j=0;j<4;j++){ acc[i][j][0]=0.f;acc[i][j][1]=0.f;acc[i][j][2]=0.f;acc[i][j][3]=0.f; }

  for (int kk = 0; kk < KD_; kk += 32) {
    STAGE_BF16(oldbf, m0, Asb);
    STAGE_BF16(Wgbf, DEL_ + ncol0, Bsb);
    __syncthreads();
    bf16x8 af[4], bff[4];
    #pragma unroll
    for (int i=0;i<4;i++) af[i]  = *(const bf16x8*)&Asb[(wm*64 + i*16 + lm)*32 + lq*8];
    #pragma unroll
    for (int j=0;j<4;j++) bff[j] = *(const bf16x8*)&Bsb[(wn*64 + j*16 + lm)*32 + lq*8];
    #pragma unroll
    for (int i=0;i<4;i++)
      #pragma unroll
      for (int j=0;j<4;j++)
        acc[i][j] = __builtin_amdgcn_mfma_f32_16x16x32_bf16(af[i], bff[j], acc[i][j], 0,0,0);
    __syncthreads();
  }

  // epilogue: p[nl][i][r] = sum over cols (u-dim) of (acc+bg)*u0
  float bgv[4];
  #pragma unroll
  for (int j=0;j<4;j++) bgv[j] = bg[DEL_ + ncol0 + wn*64 + j*16 + lm];
  float p[2][4][4];
  #pragma unroll
  for (int a=0;a<2;a++)
    #pragma unroll
    for (int i=0;i<4;i++)
      #pragma unroll
      for (int r=0;r<4;r++) p[a][i][r]=0.f;
  #pragma unroll
  for (int i=0;i<4;i++){
    #pragma unroll
    for (int r=0;r<4;r++){
      int m = m0 + wm*64 + i*16 + lq*4 + r;
      int b = m >> 7, l = m & 127;
      const float* urow = u + ((size_t)(b<<8) + 127 + l)*U_;
      #pragma unroll
      for (int j=0;j<4;j++){
        float uu = urow[(j&1)*16 + lm];
        p[j>>1][i][r] += (acc[i][j][r] + bgv[j]) * uu;
      }
    }
  }
  #pragma unroll
  for (int mk = 1; mk < 16; mk <<= 1){
    #pragma unroll
    for (int a=0;a<2;a++)
      #pragma unroll
      for (int i=0;i<4;i++)
        #pragma unroll
        for (int r=0;r<4;r++) p[a][i][r] += __shfl_xor(p[a][i][r], mk);
  }
  if (lm == 0){
    #pragma unroll
    for (int nl=0;nl<2;nl++){
      int n = ((ncol0 + wn*64 + nl*32) >> 5);
      #pragma unroll
      for (int i=0;i<4;i++)
        #pragma unroll
        for (int r=0;r<4;r++){
          int m = m0 + wm*64 + i*16 + lq*4 + r;
          wbuf[(size_t)m*N_ + n] = coef[(size_t)m*N_ + n] * p[nl][i][r];
        }
    }
  }
}

// ---------------- sequential scan ----------------
__global__ void k_scan(const float* __restrict__ P, const float* __restrict__ dA,
                       const float* __restrict__ w, float* __restrict__ zall){
  int b = blockIdx.x;
  int n = threadIdx.x;
  float z = P[(size_t)((b<<7) + 127)*N_ + n];
  #pragma unroll 4
  for (int l = 0; l < L_; l++) {
    size_t idx = (size_t)((b<<7) + l)*N_ + n;
    z = z * dA[idx] + w[idx];
    zall[idx] = z;
  }
}

// ---------------- C-path MFMA: y[m,s] += sum_n (old@WgC^T + bg)[m,n*64+s] * z[m,n] ----------------
__global__ __launch_bounds__(256, 2) void k_cmfma(
    const bf16_t* __restrict__ oldbf, const bf16_t* __restrict__ Wgbf,
    const float* __restrict__ bg, const float* __restrict__ zall,
    float* __restrict__ ybuf){
  __shared__ union {
    struct { bf16_t A[128*32]; bf16_t B[128*32]; } st;
    float ylds[128][64];
  } sm;
  int tid = threadIdx.x;
  int wave = tid >> 6, lane = tid & 63;
  int wm = wave & 1, wn = wave >> 1;
  int mt = blockIdx.y, grp = blockIdx.x;
  int m0 = mt*128;
  int srow = lane >> 2, scol = (lane & 3)*8;
  int lm = lane & 15, lq = lane >> 4;

  f32x4 yacc[4][4];
  #pragma unroll
  for (int i=0;i<4;i++)
    #pragma unroll
    for (int j=0;j<4;j++){ yacc[i][j][0]=0.f;yacc[i][j][1]=0.f;yacc[i][j][2]=0.f;yacc[i][j][3]=0.f; }

  for (int it = 0; it < 4; it++) {
    int ncol0 = (grp*4 + it)*128;
    f32x4 acc[4][4];
    #pragma unroll
    for (int i=0;i<4;i++)
      #pragma unroll
      for (int j=0;j<4;j++){ acc[i][j][0]=0.f;acc[i][j][1]=0.f;acc[i][j][2]=0.f;acc[i][j][3]=0.f; }

    for (int kk = 0; kk < KD_; kk += 32) {
      STAGE_BF16(oldbf, m0, sm.st.A);
      STAGE_BF16(Wgbf, CM_BASE + ncol0, sm.st.B);
      __syncthreads();
      bf16x8 af[4], bff[4];
      #pragma unroll
      for (int i=0;i<4;i++) af[i]  = *(const bf16x8*)&sm.st.A[(wm*64 + i*16 + lm)*32 + lq*8];
      #pragma unroll
      for (int j=0;j<4;j++) bff[j] = *(const bf16x8*)&sm.st.B[(wn*64 + j*16 + lm)*32 + lq*8];
      #pragma unroll
      for (int i=0;i<4;i++)
        #pragma unroll
        for (int j=0;j<4;j++)
          acc[i][j] = __builtin_amdgcn_mfma_f32_16x16x32_bf16(af[i], bff[j], acc[i][j], 0,0,0);
      __syncthreads();
    }

    int n = (ncol0 >> 6) + wn;
    float bgv[4];
    #pragma unroll
    for (int j=0;j<4;j++) bgv[j] = bg[CM_BASE + ncol0 + wn*64 + j*16 + lm];
    #pragma unroll
    for (int i=0;i<4;i++){
      #pragma unroll
      for (int r=0;r<4;r++){
        int m = m0 + wm*64 + i*16 + lq*4 + r;
        float zv = zall[(size_t)m*N_ + n];
        #pragma unroll
        for (int j=0;j<4;j++)
          yacc[i][j][r] += (acc[i][j][r] + bgv[j]) * zv;
      }
    }
  }

  // merge the two n-halves (wn) through LDS, then atomic partial into ybuf
  __syncthreads();
  if (wn == 1){
    #pragma unroll
    for (int i=0;i<4;i++)
      #pragma unroll
      for (int j=0;j<4;j++)
        #pragma unroll
        for (int r=0;r<4;r++){
          int ml = wm*64 + i*16 + lq*4 + r;
          sm.ylds[ml][j*16 + lm] = yacc[i][j][r];
        }
  }
  __syncthreads();
  if (wn == 0){
    #pragma unroll
    for (int i=0;i<4;i++)
      #pragma unroll
      for (int j=0;j<4;j++)
        #pragma unroll
        for (int r=0;r<4;r++){
          int ml = wm*64 + i*16 + lq*4 + r;
          int s = j*16 + lm;
          atomicAdd(&ybuf[(size_t)(m0+ml)*S_ + s], yacc[i][j][r] + sm.ylds[ml][s]);
        }
  }
}

// ---------------- finalize + loss ----------------
__global__ void k_finalize(const float* __restrict__ y, const float* __restrict__ x,
                           float* __restrict__ out, float* __restrict__ partial){
  __shared__ float red[256];
  int tid = threadIdx.x;
  float ls = 0.f;
  #pragma unroll
  for (int q = 0; q < 2; q++) {
    int e = blockIdx.x*512 + q*256 + tid;
    int m = e >> 6, s = e & 63;
    int b = m >> 7, l = m & 127;
    float yv = y[e];
    out[1 + (size_t)((l<<4) + b)*S_ + s] = yv;
    float xv = x[((size_t)(b<<8) + 128 + l)*S_ + s];
    float d = yv - xv;
    ls += d*d;
  }
  red[tid] = ls; __syncthreads();
  for (int st = 128; st > 0; st >>= 1) {
    if (tid < st) red[tid] += red[tid+st];
    __syncthreads();
  }
  if (tid == 0) partial[blockIdx.x] = red[0];
}

__global__ void k_loss(const float* __restrict__ partial, float* __restrict__ out){
  __shared__ float red[256];
  int tid = threadIdx.x;
  red[tid] = partial[tid]; __syncthreads();
  for (int st = 128; st > 0; st >>= 1) {
    if (tid < st) red[tid] += red[tid+st];
    __syncthreads();
  }
  if (tid == 0) out[0] = red[0] * (1.f / (float)(B_*S_*L_));
}

extern "C" void kernel_launch(void* const* d_in, const int* in_sizes, int n_in,
                              void* d_out, int out_size, void* d_ws, size_t ws_size,
                              hipStream_t stream) {
  const float* x   = (const float*)d_in[0];
  const float* u   = (const float*)d_in[1];
  const float* Ap  = (const float*)d_in[2];
  const float* W0  = (const float*)d_in[3];
  const float* b0  = (const float*)d_in[4];
  const float* W1  = (const float*)d_in[5];
  const float* b1  = (const float*)d_in[6];
  const float* cw  = (const float*)d_in[7];
  const float* cb  = (const float*)d_in[8];
  const float* Wg  = (const float*)d_in[9];
  const float* bg  = (const float*)d_in[10];
  const float* Wdt = (const float*)d_in[11];
  const float* bdt = (const float*)d_in[12];
  float* out = (float*)d_out;

  float* ws   = (float*)d_ws;
  float* Xp   = ws;                  // 131072
  float* Hh   = Xp   + 131072;       // 1048576
  float* Pp   = Hh   + 1048576;      // 524288
  float* oldb = Pp   + 524288;       // 589824
  float* draw = oldb + 589824;       // 131072
  float* dA   = draw + 131072;       // 524288
  float* coef = dA   + 524288;       // 524288
  float* wbuf = coef + 524288;       // 524288
  float* zall = wbuf + 524288;       // 524288
  float* ybuf = zall + 524288;       // 131072
  float* part = ybuf + 131072;       // 256 (pad to 512 for alignment)
  bf16_t* oldbf = (bf16_t*)(part + 512);          // 2048*288 bf16 = 294912 f32 slots
  bf16_t* Wgbf  = (bf16_t*)(part + 512 + 294912); // 24640*288 bf16 = 3548160 f32 slots

  hipMemsetAsync(ybuf, 0, (size_t)131072*sizeof(float), stream);

  // 0. Wg -> bf16 (24640*288 = 7096320 elems, /4 per thread)
  k_cvt<<<(7096320/4 + 255)/256, 256, 0, stream>>>(Wg, Wgbf, 7096320/4);
  // 1. pack x rows
  k_pack<<<(M_*S_ + 255)/256, 256, 0, stream>>>(x, Xp);
  // 2. H = relu(Xp @ W0.T + b0)
  k_gemm_tn<1><<<dim3(HID_/64, M_/64), 256, 0, stream>>>(Xp, W0, b0, Hh, M_, HID_, S_);
  // 3. P = H @ W1.T + b1
  k_gemm_tn<0><<<dim3(N_/64, M_/64), 256, 0, stream>>>(Hh, W1, b1, Pp, M_, N_, HID_);
  // 4. conv + silu -> old (fp32 + bf16)
  k_conv<<<M_, 320, 0, stream>>>(Pp, u, cw, cb, oldb, oldbf);
  // 5. delta_raw = old @ Wg[0:64].T + bg[0:64]  (fp32, precision-critical)
  k_gemm_tn<0><<<dim3(1, M_/64), 256, 0, stream>>>(oldb, Wg, bg, draw, M_, DEL_, KD_);
  // 6. dA, coef (fp32)
  k_delta<<<M_/16, 256, 0, stream>>>(draw, Wdt, bdt, Ap, dA, coef);
  // 7. w = coef * <Bm, u0>   (bf16 MFMA)
  k_bmfma<<<dim3(64, 16), 256, 0, stream>>>(oldbf, Wgbf, bg, u, coef, wbuf);
  // 8. scan -> z (fp32)
  k_scan<<<B_, N_, 0, stream>>>(Pp, dA, wbuf, zall);
  // 9. y = <Cm, z>   (bf16 MFMA, register-accumulated n-groups + atomics)
  k_cmfma<<<dim3(32, 16), 256, 0, stream>>>(oldbf, Wgbf, bg, zall, ybuf);
  // 10. ys reorder + loss
  k_finalize<<<256, 256, 0, stream>>>(ybuf, x, out, part);
  k_loss<<<1, 256, 0, stream>>>(part, out);
}

// Round 3
// 276.352 us; speedup vs baseline: 2.2084x; 1.0681x over previous
//
#include <hip/hip_runtime.h>
#include <math.h>

#define B_   16
#define L_   128
#define O_   128
#define N_   256
#define S_   64
#define U_   32
#define DEL_ 64
#define HID_ 512
#define CH_  288          // N_+U_
#define M_   2048         // B_*L_
#define KD_  288          // GEMM K for the Wg projections
#define CM_BASE (DEL_ + N_*U_)   // 8256

typedef __bf16 bf16_t;
typedef bf16_t bf16x8 __attribute__((ext_vector_type(8)));
typedef bf16_t bf16x4 __attribute__((ext_vector_type(4)));
typedef float  f32x4  __attribute__((ext_vector_type(4)));

#define AS1(p) ((const __attribute__((address_space(1))) void*)(unsigned long long)(const void*)(p))
#define AS3(p) ((__attribute__((address_space(3))) void*)(unsigned int)(unsigned long long)(const void*)(p))

__device__ __forceinline__ float silu_f(float x){ return x / (1.f + expf(-x)); }
__device__ __forceinline__ float softplus_f(float x){
  return fmaxf(x, 0.f) + log1pf(expf(-fabsf(x)));
}

// ---------------- pack x rows (b,t<128) -> Xp (2048 x 64) ----------------
__global__ void k_pack(const float* __restrict__ x, float* __restrict__ Xp){
  int i = blockIdx.x*256 + threadIdx.x;
  if (i >= M_*S_) return;
  int m = i >> 6, c = i & 63;
  int b = m >> 7, t = m & 127;
  Xp[i] = x[((b<<8) + t)*S_ + c];
}

// ---------------- fp32->bf16 convert ----------------
__global__ void k_cvt(const float* __restrict__ src, bf16_t* __restrict__ dst, int n4){
  int i = blockIdx.x*256 + threadIdx.x;
  if (i >= n4) return;
  float4 v = ((const float4*)src)[i];
  bf16x4 o;
  o[0] = (bf16_t)v.x; o[1] = (bf16_t)v.y; o[2] = (bf16_t)v.z; o[3] = (bf16_t)v.w;
  ((bf16x4*)dst)[i] = o;
}

// ---------------- fp32 TN GEMM (small MLP / delta GEMMs) ----------------
#define GEMM_LOAD_TILES(AB, BB, KLD)                                               \
  { _Pragma("unroll")                                                              \
    for (int q = 0; q < 2; q++) {                                                  \
      int idx = tid + q*256; int row = idx >> 3; int c4 = idx & 7;                 \
      float4 av = *(const float4*)((AB) + (size_t)row*(KLD) + kk + c4*4);          \
      float4 bv = *(const float4*)((BB) + (size_t)row*(KLD) + kk + c4*4);          \
      As[c4*4+0][row]=av.x; As[c4*4+1][row]=av.y;                                  \
      As[c4*4+2][row]=av.z; As[c4*4+3][row]=av.w;                                  \
      Bs[c4*4+0][row]=bv.x; Bs[c4*4+1][row]=bv.y;                                  \
      Bs[c4*4+2][row]=bv.z; Bs[c4*4+3][row]=bv.w;                                  \
    } }

#define GEMM_MMA32()                                                               \
  { _Pragma("unroll")                                                              \
    for (int k = 0; k < 32; k++) {                                                 \
      float4 a4 = *(const float4*)&As[k][ty*4];                                    \
      float4 b4 = *(const float4*)&Bs[k][tx*4];                                    \
      float av[4] = {a4.x,a4.y,a4.z,a4.w};                                         \
      float bv[4] = {b4.x,b4.y,b4.z,b4.w};                                         \
      _Pragma("unroll") for (int i=0;i<4;i++)                                      \
        _Pragma("unroll") for (int j=0;j<4;j++)                                    \
          acc[i][j] += av[i]*bv[j];                                                \
    } }

template<int RELU>
__global__ __launch_bounds__(256) void k_gemm_tn(
    const float* __restrict__ A, const float* __restrict__ B,
    const float* __restrict__ bias, float* __restrict__ C,
    int M, int N, int K){
  __shared__ __align__(16) float As[32][68];
  __shared__ __align__(16) float Bs[32][68];
  int tid = threadIdx.x, tx = tid & 15, ty = tid >> 4;
  int nt = blockIdx.x, mt = blockIdx.y;
  const float* Ab = A + (size_t)mt*64*K;
  const float* Bb = B + (size_t)nt*64*K;
  float acc[4][4] = {};
  for (int kk = 0; kk < K; kk += 32) {
    GEMM_LOAD_TILES(Ab, Bb, K);
    __syncthreads();
    GEMM_MMA32();
    __syncthreads();
  }
  #pragma unroll
  for (int i = 0; i < 4; i++) {
    int m = mt*64 + ty*4 + i;
    float4 v; float* vv = (float*)&v;
    #pragma unroll
    for (int j = 0; j < 4; j++) {
      int n = nt*64 + tx*4 + j;
      float t = acc[i][j] + bias[n];
      vv[j] = RELU ? fmaxf(t, 0.f) : t;
    }
    *(float4*)(&C[(size_t)m*N + nt*64 + tx*4]) = v;
  }
}

// ---------------- conv (depthwise K=4) + silu -> old fp32 + bf16 ----------------
__global__ void k_conv(const float* __restrict__ P, const float* __restrict__ u,
                       const float* __restrict__ cw, const float* __restrict__ cb,
                       float* __restrict__ oldb, bf16_t* __restrict__ oldbf){
  int bl = blockIdx.x;
  int b = bl >> 7, l = bl & 127;
  int c = threadIdx.x;
  if (c >= CH_) return;
  float acc = cb[c];
  #pragma unroll
  for (int k = 0; k < 4; k++) {
    int t = l + k - 1;
    if (t >= 0 && t <= O_-2) {
      float s;
      if (c < N_) s = P[((b<<7) + t)*N_ + c];
      else        s = u[((b<<8) + t)*U_ + (c - N_)];
      acc += silu_f(s) * cw[c*4 + k];
    }
  }
  float v = silu_f(acc);
  oldb[(size_t)bl*CH_ + c]  = v;
  oldbf[(size_t)bl*CH_ + c] = (bf16_t)v;
}

// ---------------- delta path ----------------
__global__ __launch_bounds__(256) void k_delta(
    const float* __restrict__ draw, const float* __restrict__ Wdt,
    const float* __restrict__ bdt, const float* __restrict__ Ap,
    float* __restrict__ dA, float* __restrict__ coef){
  __shared__ float dr[16][64];
  int tid = threadIdx.x;
  int m0 = blockIdx.x * 16;
  for (int f = tid; f < 16*64; f += 256)
    dr[f>>6][f&63] = draw[(size_t)(m0 + (f>>6))*64 + (f&63)];
  __syncthreads();
  int n = tid;
  float wrow[64];
  #pragma unroll
  for (int d = 0; d < 64; d++) wrow[d] = Wdt[n*64 + d];
  float a0 = Ap[n];
  float a = -(a0 > 0.f ? a0 : expm1f(a0));
  float inva = 1.f / a;
  float bd = bdt[n];
  for (int r = 0; r < 16; r++) {
    float s = bd;
    #pragma unroll
    for (int d = 0; d < 64; d++) s += dr[r][d] * wrow[d];
    float dd = softplus_f(s);
    float e  = expf(dd * a);
    size_t m = m0 + r;
    dA[m*N_ + n]   = e;
    coef[m*N_ + n] = (e - 1.f) * inva;
  }
}

// ================= MFMA staging: 128x32 bf16 tile, XOR-swizzled =================
// LDS dest is forced to base + lane*16B (row=lane>>2, chunk p=lane&3).
// We permute the GLOBAL chunk each lane fetches: c = p ^ ((row>>1)&3), so that
// stored chunk position p holds global chunk p ^ ((row>>1)&3). Coalescing is
// preserved (4 lanes of a row cover one 64B segment, permuted within it).
// Read side: fragment for row lm, chunk lq lives at chunk (lq ^ ((lm>>1)&3)).
#define STAGE_BF16(GBASE, ROW0G, LDSARR)                                            \
  { _Pragma("unroll")                                                               \
    for (int q = 0; q < 2; q++) {                                                   \
      int r0 = (wave*2 + q)*16;                                                     \
      const bf16_t* gp = (GBASE) + (size_t)((ROW0G) + r0 + srow)*KD_ + kk + scol;   \
      __builtin_amdgcn_global_load_lds(AS1(gp), AS3(&(LDSARR)[r0*32]), 16, 0, 0);   \
    } }

// ---------------- B-path MFMA ----------------
__global__ __launch_bounds__(256, 4) void k_bmfma(
    const bf16_t* __restrict__ oldbf, const bf16_t* __restrict__ Wgbf,
    const float* __restrict__ bg, const float* __restrict__ u,
    const float* __restrict__ coef, float* __restrict__ wbuf){
  __shared__ __align__(16) bf16_t Asb[128*32];
  __shared__ __align__(16) bf16_t Bsb[128*32];
  int tid = threadIdx.x;
  int wave = tid >> 6, lane = tid & 63;
  int wm = wave & 1, wn = wave >> 1;
  int mt = blockIdx.y, nt = blockIdx.x;
  int m0 = mt*128, ncol0 = nt*128;
  int srow = lane >> 2;
  int scol = (((lane & 3) ^ ((srow >> 1) & 3))) * 8;   // swizzled global chunk
  int lm = lane & 15, lq = lane >> 4;
  int swz = (lm >> 1) & 3;

  f32x4 acc[4][4];
  #pragma unroll
  for (int i=0;i<4;i++)
    #pragma unroll
    for (int j=0;j<4;j++){ acc[i][j][0]=0.f;acc[i][j][1]=0.f;acc[i][j][2]=0.f;acc[i][j][3]=0.f; }

  for (int kk = 0; kk < KD_; kk += 32) {
    STAGE_BF16(oldbf, m0, Asb);
    STAGE_BF16(Wgbf, DEL_ + ncol0, Bsb);
    __syncthreads();
    bf16x8 af[4], bff[4];
    #pragma unroll
    for (int i=0;i<4;i++) af[i]  = *(const bf16x8*)&Asb[(wm*64 + i*16 + lm)*32 + (lq^swz)*8];
    #pragma unroll
    for (int j=0;j<4;j++) bff[j] = *(const bf16x8*)&Bsb[(wn*64 + j*16 + lm)*32 + (lq^swz)*8];
    #pragma unroll
    for (int i=0;i<4;i++)
      #pragma unroll
      for (int j=0;j<4;j++)
        acc[i][j] = __builtin_amdgcn_mfma_f32_16x16x32_bf16(af[i], bff[j], acc[i][j], 0,0,0);
    __syncthreads();
  }

  float bgv[4];
  #pragma unroll
  for (int j=0;j<4;j++) bgv[j] = bg[DEL_ + ncol0 + wn*64 + j*16 + lm];
  float p[2][4][4];
  #pragma unroll
  for (int a=0;a<2;a++)
    #pragma unroll
    for (int i=0;i<4;i++)
      #pragma unroll
      for (int r=0;r<4;r++) p[a][i][r]=0.f;
  #pragma unroll
  for (int i=0;i<4;i++){
    #pragma unroll
    for (int r=0;r<4;r++){
      int m = m0 + wm*64 + i*16 + lq*4 + r;
      int b = m >> 7, l = m & 127;
      const float* urow = u + ((size_t)(b<<8) + 127 + l)*U_;
      #pragma unroll
      for (int j=0;j<4;j++){
        float uu = urow[(j&1)*16 + lm];
        p[j>>1][i][r] += (acc[i][j][r] + bgv[j]) * uu;
      }
    }
  }
  #pragma unroll
  for (int mk = 1; mk < 16; mk <<= 1){
    #pragma unroll
    for (int a=0;a<2;a++)
      #pragma unroll
      for (int i=0;i<4;i++)
        #pragma unroll
        for (int r=0;r<4;r++) p[a][i][r] += __shfl_xor(p[a][i][r], mk);
  }
  if (lm == 0){
    #pragma unroll
    for (int nl=0;nl<2;nl++){
      int n = ((ncol0 + wn*64 + nl*32) >> 5);
      #pragma unroll
      for (int i=0;i<4;i++)
        #pragma unroll
        for (int r=0;r<4;r++){
          int m = m0 + wm*64 + i*16 + lq*4 + r;
          wbuf[(size_t)m*N_ + n] = coef[(size_t)m*N_ + n] * p[nl][i][r];
        }
    }
  }
}

// ---------------- sequential scan ----------------
__global__ void k_scan(const float* __restrict__ P, const float* __restrict__ dA,
                       const float* __restrict__ w, float* __restrict__ zall){
  int b = blockIdx.x;
  int n = threadIdx.x;
  float z = P[(size_t)((b<<7) + 127)*N_ + n];
  #pragma unroll 4
  for (int l = 0; l < L_; l++) {
    size_t idx = (size_t)((b<<7) + l)*N_ + n;
    z = z * dA[idx] + w[idx];
    zall[idx] = z;
  }
}

// ---------------- C-path MFMA ----------------
__global__ __launch_bounds__(256, 2) void k_cmfma(
    const bf16_t* __restrict__ oldbf, const bf16_t* __restrict__ Wgbf,
    const float* __restrict__ bg, const float* __restrict__ zall,
    float* __restrict__ ybuf){
  __shared__ union {
    struct { bf16_t A[128*32]; bf16_t B[128*32]; } st;
    float ylds[128][64];
  } sm;
  int tid = threadIdx.x;
  int wave = tid >> 6, lane = tid & 63;
  int wm = wave & 1, wn = wave >> 1;
  int mt = blockIdx.y, grp = blockIdx.x;
  int m0 = mt*128;
  int srow = lane >> 2;
  int scol = (((lane & 3) ^ ((srow >> 1) & 3))) * 8;
  int lm = lane & 15, lq = lane >> 4;
  int swz = (lm >> 1) & 3;

  f32x4 yacc[4][4];
  #pragma unroll
  for (int i=0;i<4;i++)
    #pragma unroll
    for (int j=0;j<4;j++){ yacc[i][j][0]=0.f;yacc[i][j][1]=0.f;yacc[i][j][2]=0.f;yacc[i][j][3]=0.f; }

  for (int it = 0; it < 4; it++) {
    int ncol0 = (grp*4 + it)*128;
    f32x4 acc[4][4];
    #pragma unroll
    for (int i=0;i<4;i++)
      #pragma unroll
      for (int j=0;j<4;j++){ acc[i][j][0]=0.f;acc[i][j][1]=0.f;acc[i][j][2]=0.f;acc[i][j][3]=0.f; }

    for (int kk = 0; kk < KD_; kk += 32) {
      STAGE_BF16(oldbf, m0, sm.st.A);
      STAGE_BF16(Wgbf, CM_BASE + ncol0, sm.st.B);
      __syncthreads();
      bf16x8 af[4], bff[4];
      #pragma unroll
      for (int i=0;i<4;i++) af[i]  = *(const bf16x8*)&sm.st.A[(wm*64 + i*16 + lm)*32 + (lq^swz)*8];
      #pragma unroll
      for (int j=0;j<4;j++) bff[j] = *(const bf16x8*)&sm.st.B[(wn*64 + j*16 + lm)*32 + (lq^swz)*8];
      #pragma unroll
      for (int i=0;i<4;i++)
        #pragma unroll
        for (int j=0;j<4;j++)
          acc[i][j] = __builtin_amdgcn_mfma_f32_16x16x32_bf16(af[i], bff[j], acc[i][j], 0,0,0);
      __syncthreads();
    }

    int n = (ncol0 >> 6) + wn;
    float bgv[4];
    #pragma unroll
    for (int j=0;j<4;j++) bgv[j] = bg[CM_BASE + ncol0 + wn*64 + j*16 + lm];
    #pragma unroll
    for (int i=0;i<4;i++){
      #pragma unroll
      for (int r=0;r<4;r++){
        int m = m0 + wm*64 + i*16 + lq*4 + r;
        float zv = zall[(size_t)m*N_ + n];
        #pragma unroll
        for (int j=0;j<4;j++)
          yacc[i][j][r] += (acc[i][j][r] + bgv[j]) * zv;
      }
    }
  }

  __syncthreads();
  if (wn == 1){
    #pragma unroll
    for (int i=0;i<4;i++)
      #pragma unroll
      for (int j=0;j<4;j++)
        #pragma unroll
        for (int r=0;r<4;r++){
          int ml = wm*64 + i*16 + lq*4 + r;
          sm.ylds[ml][j*16 + lm] = yacc[i][j][r];
        }
  }
  __syncthreads();
  if (wn == 0){
    #pragma unroll
    for (int i=0;i<4;i++)
      #pragma unroll
      for (int j=0;j<4;j++)
        #pragma unroll
        for (int r=0;r<4;r++){
          int ml = wm*64 + i*16 + lq*4 + r;
          int s = j*16 + lm;
          atomicAdd(&ybuf[(size_t)(m0+ml)*S_ + s], yacc[i][j][r] + sm.ylds[ml][s]);
        }
  }
}

// ---------------- finalize + loss ----------------
__global__ void k_finalize(const float* __restrict__ y, const float* __restrict__ x,
                           float* __restrict__ out, float* __restrict__ partial){
  __shared__ float red[256];
  int tid = threadIdx.x;
  float ls = 0.f;
  #pragma unroll
  for (int q = 0; q < 2; q++) {
    int e = blockIdx.x*512 + q*256 + tid;
    int m = e >> 6, s = e & 63;
    int b = m >> 7, l = m & 127;
    float yv = y[e];
    out[1 + (size_t)((l<<4) + b)*S_ + s] = yv;
    float xv = x[((size_t)(b<<8) + 128 + l)*S_ + s];
    float d = yv - xv;
    ls += d*d;
  }
  red[tid] = ls; __syncthreads();
  for (int st = 128; st > 0; st >>= 1) {
    if (tid < st) red[tid] += red[tid+st];
    __syncthreads();
  }
  if (tid == 0) partial[blockIdx.x] = red[0];
}

__global__ void k_loss(const float* __restrict__ partial, float* __restrict__ out){
  __shared__ float red[256];
  int tid = threadIdx.x;
  red[tid] = partial[tid]; __syncthreads();
  for (int st = 128; st > 0; st >>= 1) {
    if (tid < st) red[tid] += red[tid+st];
    __syncthreads();
  }
  if (tid == 0) out[0] = red[0] * (1.f / (float)(B_*S_*L_));
}

extern "C" void kernel_launch(void* const* d_in, const int* in_sizes, int n_in,
                              void* d_out, int out_size, void* d_ws, size_t ws_size,
                              hipStream_t stream) {
  const float* x   = (const float*)d_in[0];
  const float* u   = (const float*)d_in[1];
  const float* Ap  = (const float*)d_in[2];
  const float* W0  = (const float*)d_in[3];
  const float* b0  = (const float*)d_in[4];
  const float* W1  = (const float*)d_in[5];
  const float* b1  = (const float*)d_in[6];
  const float* cw  = (const float*)d_in[7];
  const float* cb  = (const float*)d_in[8];
  const float* Wg  = (const float*)d_in[9];
  const float* bg  = (const float*)d_in[10];
  const float* Wdt = (const float*)d_in[11];
  const float* bdt = (const float*)d_in[12];
  float* out = (float*)d_out;

  float* ws   = (float*)d_ws;
  float* Xp   = ws;                  // 131072
  float* Hh   = Xp   + 131072;       // 1048576
  float* Pp   = Hh   + 1048576;      // 524288
  float* oldb = Pp   + 524288;       // 589824
  float* draw = oldb + 589824;       // 131072
  float* dA   = draw + 131072;       // 524288
  float* coef = dA   + 524288;       // 524288
  float* wbuf = coef + 524288;       // 524288
  float* zall = wbuf + 524288;       // 524288
  float* ybuf = zall + 524288;       // 131072
  float* part = ybuf + 131072;       // 256 (pad to 512)
  bf16_t* oldbf = (bf16_t*)(part + 512);
  bf16_t* Wgbf  = (bf16_t*)(part + 512 + 294912);

  hipMemsetAsync(ybuf, 0, (size_t)131072*sizeof(float), stream);

  k_cvt<<<(7096320/4 + 255)/256, 256, 0, stream>>>(Wg, Wgbf, 7096320/4);
  k_pack<<<(M_*S_ + 255)/256, 256, 0, stream>>>(x, Xp);
  k_gemm_tn<1><<<dim3(HID_/64, M_/64), 256, 0, stream>>>(Xp, W0, b0, Hh, M_, HID_, S_);
  k_gemm_tn<0><<<dim3(N_/64, M_/64), 256, 0, stream>>>(Hh, W1, b1, Pp, M_, N_, HID_);
  k_conv<<<M_, 320, 0, stream>>>(Pp, u, cw, cb, oldb, oldbf);
  k_gemm_tn<0><<<dim3(1, M_/64), 256, 0, stream>>>(oldb, Wg, bg, draw, M_, DEL_, KD_);
  k_delta<<<M_/16, 256, 0, stream>>>(draw, Wdt, bdt, Ap, dA, coef);
  k_bmfma<<<dim3(64, 16), 256, 0, stream>>>(oldbf, Wgbf, bg, u, coef, wbuf);
  k_scan<<<B_, N_, 0, stream>>>(Pp, dA, wbuf, zall);
  k_cmfma<<<dim3(32, 16), 256, 0, stream>>>(oldbf, Wgbf, bg, zall, ybuf);
  k_finalize<<<256, 256, 0, stream>>>(ybuf, x, out, part);
  k_loss<<<1, 256, 0, stream>>>(part, out);
}

// Round 4
// 256.572 us; speedup vs baseline: 2.3787x; 1.0771x over previous
//
#include <hip/hip_runtime.h>
#include <math.h>

#define B_   16
#define L_   128
#define O_   128
#define N_   256
#define S_   64
#define U_   32
#define DEL_ 64
#define HID_ 512
#define CH_  288          // N_+U_
#define M_   2048         // B_*L_
#define KD_  288          // GEMM K for the Wg projections
#define CM_BASE (DEL_ + N_*U_)   // 8256
#define NSLICE 32

typedef __bf16 bf16_t;
typedef bf16_t bf16x8 __attribute__((ext_vector_type(8)));
typedef bf16_t bf16x4 __attribute__((ext_vector_type(4)));
typedef float  f32x4  __attribute__((ext_vector_type(4)));

#define AS1(p) ((const __attribute__((address_space(1))) void*)(unsigned long long)(const void*)(p))
#define AS3(p) ((__attribute__((address_space(3))) void*)(unsigned int)(unsigned long long)(const void*)(p))

__device__ __forceinline__ float silu_f(float x){ return x / (1.f + expf(-x)); }
__device__ __forceinline__ float softplus_f(float x){
  return fmaxf(x, 0.f) + log1pf(expf(-fabsf(x)));
}

// ---------------- pack x rows (b,t<128) -> Xp (2048 x 64) ----------------
__global__ void k_pack(const float* __restrict__ x, float* __restrict__ Xp){
  int i = blockIdx.x*256 + threadIdx.x;
  if (i >= M_*S_) return;
  int m = i >> 6, c = i & 63;
  int b = m >> 7, t = m & 127;
  Xp[i] = x[((b<<8) + t)*S_ + c];
}

// ---------------- fp32->bf16 convert (8 elems/thread) ----------------
__global__ void k_cvt(const float* __restrict__ src, bf16_t* __restrict__ dst, int n8){
  int i = blockIdx.x*256 + threadIdx.x;
  if (i >= n8) return;
  float4 a = ((const float4*)src)[2*i];
  float4 b = ((const float4*)src)[2*i+1];
  bf16x8 o;
  o[0]=(bf16_t)a.x; o[1]=(bf16_t)a.y; o[2]=(bf16_t)a.z; o[3]=(bf16_t)a.w;
  o[4]=(bf16_t)b.x; o[5]=(bf16_t)b.y; o[6]=(bf16_t)b.z; o[7]=(bf16_t)b.w;
  ((bf16x8*)dst)[i] = o;
}

// ---------------- fp32 TN GEMM (small MLP / delta GEMMs) ----------------
#define GEMM_LOAD_TILES(AB, BB, KLD)                                               \
  { _Pragma("unroll")                                                              \
    for (int q = 0; q < 2; q++) {                                                  \
      int idx = tid + q*256; int row = idx >> 3; int c4 = idx & 7;                 \
      float4 av = *(const float4*)((AB) + (size_t)row*(KLD) + kk + c4*4);          \
      float4 bv = *(const float4*)((BB) + (size_t)row*(KLD) + kk + c4*4);          \
      As[c4*4+0][row]=av.x; As[c4*4+1][row]=av.y;                                  \
      As[c4*4+2][row]=av.z; As[c4*4+3][row]=av.w;                                  \
      Bs[c4*4+0][row]=bv.x; Bs[c4*4+1][row]=bv.y;                                  \
      Bs[c4*4+2][row]=bv.z; Bs[c4*4+3][row]=bv.w;                                  \
    } }

#define GEMM_MMA32()                                                               \
  { _Pragma("unroll")                                                              \
    for (int k = 0; k < 32; k++) {                                                 \
      float4 a4 = *(const float4*)&As[k][ty*4];                                    \
      float4 b4 = *(const float4*)&Bs[k][tx*4];                                    \
      float av[4] = {a4.x,a4.y,a4.z,a4.w};                                         \
      float bv[4] = {b4.x,b4.y,b4.z,b4.w};                                         \
      _Pragma("unroll") for (int i=0;i<4;i++)                                      \
        _Pragma("unroll") for (int j=0;j<4;j++)                                    \
          acc[i][j] += av[i]*bv[j];                                                \
    } }

template<int RELU>
__global__ __launch_bounds__(256) void k_gemm_tn(
    const float* __restrict__ A, const float* __restrict__ B,
    const float* __restrict__ bias, float* __restrict__ C,
    int M, int N, int K){
  __shared__ __align__(16) float As[32][68];
  __shared__ __align__(16) float Bs[32][68];
  int tid = threadIdx.x, tx = tid & 15, ty = tid >> 4;
  int nt = blockIdx.x, mt = blockIdx.y;
  const float* Ab = A + (size_t)mt*64*K;
  const float* Bb = B + (size_t)nt*64*K;
  float acc[4][4] = {};
  for (int kk = 0; kk < K; kk += 32) {
    GEMM_LOAD_TILES(Ab, Bb, K);
    __syncthreads();
    GEMM_MMA32();
    __syncthreads();
  }
  #pragma unroll
  for (int i = 0; i < 4; i++) {
    int m = mt*64 + ty*4 + i;
    float4 v; float* vv = (float*)&v;
    #pragma unroll
    for (int j = 0; j < 4; j++) {
      int n = nt*64 + tx*4 + j;
      float t = acc[i][j] + bias[n];
      vv[j] = RELU ? fmaxf(t, 0.f) : t;
    }
    *(float4*)(&C[(size_t)m*N + nt*64 + tx*4]) = v;
  }
}

// ---------------- conv (depthwise K=4) + silu -> old fp32 + bf16 ----------------
__global__ void k_conv(const float* __restrict__ P, const float* __restrict__ u,
                       const float* __restrict__ cw, const float* __restrict__ cb,
                       float* __restrict__ oldb, bf16_t* __restrict__ oldbf){
  int bl = blockIdx.x;
  int b = bl >> 7, l = bl & 127;
  int c = threadIdx.x;
  if (c >= CH_) return;
  float acc = cb[c];
  #pragma unroll
  for (int k = 0; k < 4; k++) {
    int t = l + k - 1;
    if (t >= 0 && t <= O_-2) {
      float s;
      if (c < N_) s = P[((b<<7) + t)*N_ + c];
      else        s = u[((b<<8) + t)*U_ + (c - N_)];
      acc += silu_f(s) * cw[c*4 + k];
    }
  }
  float v = silu_f(acc);
  oldb[(size_t)bl*CH_ + c]  = v;
  oldbf[(size_t)bl*CH_ + c] = (bf16_t)v;
}

// ---------------- delta path ----------------
__global__ __launch_bounds__(256) void k_delta(
    const float* __restrict__ draw, const float* __restrict__ Wdt,
    const float* __restrict__ bdt, const float* __restrict__ Ap,
    float* __restrict__ dA, float* __restrict__ coef){
  __shared__ float dr[16][64];
  int tid = threadIdx.x;
  int m0 = blockIdx.x * 16;
  for (int f = tid; f < 16*64; f += 256)
    dr[f>>6][f&63] = draw[(size_t)(m0 + (f>>6))*64 + (f&63)];
  __syncthreads();
  int n = tid;
  float wrow[64];
  #pragma unroll
  for (int d = 0; d < 64; d++) wrow[d] = Wdt[n*64 + d];
  float a0 = Ap[n];
  float a = -(a0 > 0.f ? a0 : expm1f(a0));
  float inva = 1.f / a;
  float bd = bdt[n];
  for (int r = 0; r < 16; r++) {
    float s = bd;
    #pragma unroll
    for (int d = 0; d < 64; d++) s += dr[r][d] * wrow[d];
    float dd = softplus_f(s);
    float e  = expf(dd * a);
    size_t m = m0 + r;
    dA[m*N_ + n]   = e;
    coef[m*N_ + n] = (e - 1.f) * inva;
  }
}

// ================= fragment-order staging =================
// global_load_lds: per-lane GLOBAL address, LDS dest forced to base+lane*16B.
// We stage so LDS holds tiles in MFMA-fragment order: group g (16 rows x 32 k)
// occupies 1024B; lane L of the staging wave fetches row (g*16 + (L&15)),
// k-chunk (L>>4). Then the fragment ds_read for group g is simply
// 16B at (g*1024 + lane*16) -- strictly sequential, conflict-free, and the
// global footprint per instruction is the same 16 rows x 64B (permuted lanes,
// same coalescing segments).
#define STAGE_FR(GBASE, ROW0G, LDSARR)                                              \
  { _Pragma("unroll")                                                               \
    for (int q = 0; q < 2; q++) {                                                   \
      int g = wave*2 + q;                                                           \
      const bf16_t* gp = (GBASE) + (size_t)((ROW0G) + g*16 + lm)*KD_ + kk + lq*8;   \
      __builtin_amdgcn_global_load_lds(AS1(gp), AS3(&(LDSARR)[g*512]), 16, 0, 0);   \
    } }

// ---------------- B-path MFMA ----------------
__global__ __launch_bounds__(256, 4) void k_bmfma(
    const bf16_t* __restrict__ oldbf, const bf16_t* __restrict__ Wgbf,
    const float* __restrict__ bg, const float* __restrict__ u,
    const float* __restrict__ coef, float* __restrict__ wbuf){
  __shared__ __align__(16) bf16_t Asb[128*32];
  __shared__ __align__(16) bf16_t Bsb[128*32];
  int tid = threadIdx.x;
  int wave = tid >> 6, lane = tid & 63;
  int wm = wave & 1, wn = wave >> 1;
  int mt = blockIdx.y, nt = blockIdx.x;
  int m0 = mt*128, ncol0 = nt*128;
  int lm = lane & 15, lq = lane >> 4;

  f32x4 acc[4][4];
  #pragma unroll
  for (int i=0;i<4;i++)
    #pragma unroll
    for (int j=0;j<4;j++){ acc[i][j][0]=0.f;acc[i][j][1]=0.f;acc[i][j][2]=0.f;acc[i][j][3]=0.f; }

  for (int kk = 0; kk < KD_; kk += 32) {
    STAGE_FR(oldbf, m0, Asb);
    STAGE_FR(Wgbf, DEL_ + ncol0, Bsb);
    __syncthreads();
    bf16x8 af[4], bff[4];
    #pragma unroll
    for (int i=0;i<4;i++) af[i]  = *(const bf16x8*)&Asb[(wm*4 + i)*512 + lane*8];
    #pragma unroll
    for (int j=0;j<4;j++) bff[j] = *(const bf16x8*)&Bsb[(wn*4 + j)*512 + lane*8];
    #pragma unroll
    for (int i=0;i<4;i++)
      #pragma unroll
      for (int j=0;j<4;j++)
        acc[i][j] = __builtin_amdgcn_mfma_f32_16x16x32_bf16(af[i], bff[j], acc[i][j], 0,0,0);
    __syncthreads();
  }

  float bgv[4];
  #pragma unroll
  for (int j=0;j<4;j++) bgv[j] = bg[DEL_ + ncol0 + wn*64 + j*16 + lm];
  float p[2][4][4];
  #pragma unroll
  for (int a=0;a<2;a++)
    #pragma unroll
    for (int i=0;i<4;i++)
      #pragma unroll
      for (int r=0;r<4;r++) p[a][i][r]=0.f;
  #pragma unroll
  for (int i=0;i<4;i++){
    #pragma unroll
    for (int r=0;r<4;r++){
      int m = m0 + wm*64 + i*16 + lq*4 + r;
      int b = m >> 7, l = m & 127;
      const float* urow = u + ((size_t)(b<<8) + 127 + l)*U_;
      #pragma unroll
      for (int j=0;j<4;j++){
        float uu = urow[(j&1)*16 + lm];
        p[j>>1][i][r] += (acc[i][j][r] + bgv[j]) * uu;
      }
    }
  }
  #pragma unroll
  for (int mk = 1; mk < 16; mk <<= 1){
    #pragma unroll
    for (int a=0;a<2;a++)
      #pragma unroll
      for (int i=0;i<4;i++)
        #pragma unroll
        for (int r=0;r<4;r++) p[a][i][r] += __shfl_xor(p[a][i][r], mk);
  }
  if (lm == 0){
    #pragma unroll
    for (int nl=0;nl<2;nl++){
      int n = ((ncol0 + wn*64 + nl*32) >> 5);
      #pragma unroll
      for (int i=0;i<4;i++)
        #pragma unroll
        for (int r=0;r<4;r++){
          int m = m0 + wm*64 + i*16 + lq*4 + r;
          wbuf[(size_t)m*N_ + n] = coef[(size_t)m*N_ + n] * p[nl][i][r];
        }
    }
  }
}

// ---------------- sequential scan (batched loads, 64 blocks x 64 threads) ----------------
__global__ void k_scan(const float* __restrict__ P, const float* __restrict__ dA,
                       const float* __restrict__ w, float* __restrict__ zall){
  int blk = blockIdx.x;             // 64
  int b = blk >> 2;
  int n = (blk & 3)*64 + threadIdx.x;
  float z = P[(size_t)((b<<7) + 127)*N_ + n];
  for (int l0 = 0; l0 < L_; l0 += 16) {
    float da[16], ww[16];
    #pragma unroll
    for (int t = 0; t < 16; t++) {
      size_t idx = (size_t)((b<<7) + l0 + t)*N_ + n;
      da[t] = dA[idx]; ww[t] = w[idx];
    }
    #pragma unroll
    for (int t = 0; t < 16; t++) {
      size_t idx = (size_t)((b<<7) + l0 + t)*N_ + n;
      z = z * da[t] + ww[t];
      zall[idx] = z;
    }
  }
}

// ---------------- C-path MFMA: per-block y partial into private slice ----------------
__global__ __launch_bounds__(256, 2) void k_cmfma(
    const bf16_t* __restrict__ oldbf, const bf16_t* __restrict__ Wgbf,
    const float* __restrict__ bg, const float* __restrict__ zall,
    float* __restrict__ ypart){
  __shared__ union {
    struct { bf16_t A[128*32]; bf16_t B[128*32]; } st;
    float ylds[128][64];
  } sm;
  int tid = threadIdx.x;
  int wave = tid >> 6, lane = tid & 63;
  int wm = wave & 1, wn = wave >> 1;
  int mt = blockIdx.y, grp = blockIdx.x;
  int m0 = mt*128;
  int lm = lane & 15, lq = lane >> 4;

  f32x4 yacc[4][4];
  #pragma unroll
  for (int i=0;i<4;i++)
    #pragma unroll
    for (int j=0;j<4;j++){ yacc[i][j][0]=0.f;yacc[i][j][1]=0.f;yacc[i][j][2]=0.f;yacc[i][j][3]=0.f; }

  for (int it = 0; it < 4; it++) {
    int ncol0 = (grp*4 + it)*128;
    f32x4 acc[4][4];
    #pragma unroll
    for (int i=0;i<4;i++)
      #pragma unroll
      for (int j=0;j<4;j++){ acc[i][j][0]=0.f;acc[i][j][1]=0.f;acc[i][j][2]=0.f;acc[i][j][3]=0.f; }

    for (int kk = 0; kk < KD_; kk += 32) {
      STAGE_FR(oldbf, m0, sm.st.A);
      STAGE_FR(Wgbf, CM_BASE + ncol0, sm.st.B);
      __syncthreads();
      bf16x8 af[4], bff[4];
      #pragma unroll
      for (int i=0;i<4;i++) af[i]  = *(const bf16x8*)&sm.st.A[(wm*4 + i)*512 + lane*8];
      #pragma unroll
      for (int j=0;j<4;j++) bff[j] = *(const bf16x8*)&sm.st.B[(wn*4 + j)*512 + lane*8];
      #pragma unroll
      for (int i=0;i<4;i++)
        #pragma unroll
        for (int j=0;j<4;j++)
          acc[i][j] = __builtin_amdgcn_mfma_f32_16x16x32_bf16(af[i], bff[j], acc[i][j], 0,0,0);
      __syncthreads();
    }

    int n = (ncol0 >> 6) + wn;
    float bgv[4];
    #pragma unroll
    for (int j=0;j<4;j++) bgv[j] = bg[CM_BASE + ncol0 + wn*64 + j*16 + lm];
    #pragma unroll
    for (int i=0;i<4;i++){
      #pragma unroll
      for (int r=0;r<4;r++){
        int m = m0 + wm*64 + i*16 + lq*4 + r;
        float zv = zall[(size_t)m*N_ + n];
        #pragma unroll
        for (int j=0;j<4;j++)
          yacc[i][j][r] += (acc[i][j][r] + bgv[j]) * zv;
      }
    }
  }

  __syncthreads();
  if (wn == 1){
    #pragma unroll
    for (int i=0;i<4;i++)
      #pragma unroll
      for (int j=0;j<4;j++)
        #pragma unroll
        for (int r=0;r<4;r++){
          int ml = wm*64 + i*16 + lq*4 + r;
          sm.ylds[ml][j*16 + lm] = yacc[i][j][r];
        }
  }
  __syncthreads();
  if (wn == 0){
    float* dst = ypart + (size_t)grp*(M_*S_);
    #pragma unroll
    for (int i=0;i<4;i++)
      #pragma unroll
      for (int j=0;j<4;j++)
        #pragma unroll
        for (int r=0;r<4;r++){
          int ml = wm*64 + i*16 + lq*4 + r;
          int s = j*16 + lm;
          dst[(size_t)(m0+ml)*S_ + s] = yacc[i][j][r] + sm.ylds[ml][s];
        }
  }
}

// ---------------- finalize: sum slices, write ys (L,B,S), loss partials ----------------
__global__ void k_finalize(const float* __restrict__ ypart, const float* __restrict__ x,
                           float* __restrict__ out, float* __restrict__ partial){
  __shared__ float red[256];
  int tid = threadIdx.x;
  float ls = 0.f;
  #pragma unroll
  for (int q = 0; q < 2; q++) {
    int e = blockIdx.x*512 + q*256 + tid;
    int m = e >> 6, s = e & 63;
    int b = m >> 7, l = m & 127;
    float yv = 0.f;
    #pragma unroll 8
    for (int g = 0; g < NSLICE; g++) yv += ypart[(size_t)g*(M_*S_) + e];
    out[1 + (size_t)((l<<4) + b)*S_ + s] = yv;
    float xv = x[((size_t)(b<<8) + 128 + l)*S_ + s];
    float d = yv - xv;
    ls += d*d;
  }
  red[tid] = ls; __syncthreads();
  for (int st = 128; st > 0; st >>= 1) {
    if (tid < st) red[tid] += red[tid+st];
    __syncthreads();
  }
  if (tid == 0) partial[blockIdx.x] = red[0];
}

__global__ void k_loss(const float* __restrict__ partial, float* __restrict__ out){
  __shared__ float red[256];
  int tid = threadIdx.x;
  red[tid] = partial[tid]; __syncthreads();
  for (int st = 128; st > 0; st >>= 1) {
    if (tid < st) red[tid] += red[tid+st];
    __syncthreads();
  }
  if (tid == 0) out[0] = red[0] * (1.f / (float)(B_*S_*L_));
}

extern "C" void kernel_launch(void* const* d_in, const int* in_sizes, int n_in,
                              void* d_out, int out_size, void* d_ws, size_t ws_size,
                              hipStream_t stream) {
  const float* x   = (const float*)d_in[0];
  const float* u   = (const float*)d_in[1];
  const float* Ap  = (const float*)d_in[2];
  const float* W0  = (const float*)d_in[3];
  const float* b0  = (const float*)d_in[4];
  const float* W1  = (const float*)d_in[5];
  const float* b1  = (const float*)d_in[6];
  const float* cw  = (const float*)d_in[7];
  const float* cb  = (const float*)d_in[8];
  const float* Wg  = (const float*)d_in[9];
  const float* bg  = (const float*)d_in[10];
  const float* Wdt = (const float*)d_in[11];
  const float* bdt = (const float*)d_in[12];
  float* out = (float*)d_out;

  float* ws   = (float*)d_ws;
  float* Xp   = ws;                  // 131072
  float* Hh   = Xp   + 131072;       // 1048576
  float* Pp   = Hh   + 1048576;      // 524288
  float* oldb = Pp   + 524288;       // 589824
  float* draw = oldb + 589824;       // 131072
  float* dA   = draw + 131072;       // 524288
  float* coef = dA   + 524288;       // 524288
  float* wbuf = coef + 524288;       // 524288
  float* zall = wbuf + 524288;       // 524288
  float* part = zall + 524288;       // 512
  bf16_t* oldbf = (bf16_t*)(part + 512);            // 294912 f32 slots
  bf16_t* Wgbf  = (bf16_t*)(part + 512 + 294912);   // 3548160 f32 slots
  float* ypart  = part + 512 + 294912 + 3548160;    // 32*131072 = 4194304

  k_cvt<<<(7096320/8 + 255)/256, 256, 0, stream>>>(Wg, Wgbf, 7096320/8);
  k_pack<<<(M_*S_ + 255)/256, 256, 0, stream>>>(x, Xp);
  k_gemm_tn<1><<<dim3(HID_/64, M_/64), 256, 0, stream>>>(Xp, W0, b0, Hh, M_, HID_, S_);
  k_gemm_tn<0><<<dim3(N_/64, M_/64), 256, 0, stream>>>(Hh, W1, b1, Pp, M_, N_, HID_);
  k_conv<<<M_, 320, 0, stream>>>(Pp, u, cw, cb, oldb, oldbf);
  k_gemm_tn<0><<<dim3(1, M_/64), 256, 0, stream>>>(oldb, Wg, bg, draw, M_, DEL_, KD_);
  k_delta<<<M_/16, 256, 0, stream>>>(draw, Wdt, bdt, Ap, dA, coef);
  k_bmfma<<<dim3(64, 16), 256, 0, stream>>>(oldbf, Wgbf, bg, u, coef, wbuf);
  k_scan<<<64, 64, 0, stream>>>(Pp, dA, wbuf, zall);
  k_cmfma<<<dim3(32, 16), 256, 0, stream>>>(oldbf, Wgbf, bg, zall, ypart);
  k_finalize<<<256, 256, 0, stream>>>(ypart, x, out, part);
  k_loss<<<1, 256, 0, stream>>>(part, out);
}